// Round 4
// baseline (154.417 us; speedup 1.0000x reference)
//
#include <hip/hip_runtime.h>

// ---------------- weight packing (1 tiny block, runs each launch) ----------------
// ws[o*32 + 0..15]  = W1[c][o]   (W1 is (16,64) row-major -> transposed row o)
// ws[o*32 + 16..31] = W2[o][c]   (W2 is (64,16) row-major -> row o)
// ws[2048 + o]      = b1[o]
__global__ void pack_weights(const float* __restrict__ W1, const float* __restrict__ b1,
                             const float* __restrict__ W2, float* __restrict__ ws) {
    int t = threadIdx.x;
    for (int idx = t; idx < 1024; idx += 256) {
        int o = idx >> 4, c = idx & 15;
        ws[o * 32 + c]      = W1[c * 64 + o];
        ws[o * 32 + 16 + c] = W2[o * 16 + c];
    }
    if (t < 64) ws[2048 + t] = b1[t];
}

// ---------------- main kernel ----------------
// TWO threads per (b,p,head) row: lane 2m handles neighbors 0..4, lane 2m+1
// handles 5..8. Doubles the wave count (8192 waves -> up to 32 waves/CU at
// VGPR<=64) to hide the vmcnt/lgkmcnt latency that capped round 3 at ~60%
// VALUBusy with only 16 waves/CU. Partial online-softmax sums combine with
// same-wave __shfl_xor(.,1) -- no LDS, no barrier. Weights remain wave-uniform
// -> scalar s_load operands.
__global__ __launch_bounds__(256)
void subattn_kernel(const float* __restrict__ q, const float* __restrict__ k,
                    const float* __restrict__ v, const float* __restrict__ pe,
                    const float* __restrict__ ws, float* __restrict__ out)
{
    const int tid = threadIdx.x;
    const int gid = blockIdx.x * 256 + tid;
    const int t   = gid & 1;            // which neighbor-half of the row
    const int r   = gid >> 1;           // row = (bp, head)
    const int h   = r & 3;
    const int bp  = r >> 2;
    const size_t qbase   = (size_t)bp * 64 + h * 16;
    const size_t rowbase = (size_t)bp * 576 + h * 16;   // 9 neighbors * 64 ch

    // q row, held in registers (both lanes of a pair read the same q: L1 hit)
    float qr[16];
    {
        const float4* q4 = (const float4*)(q + qbase);
        #pragma unroll
        for (int i = 0; i < 4; ++i) {
            float4 tq = q4[i];
            qr[4*i+0] = tq.x; qr[4*i+1] = tq.y; qr[4*i+2] = tq.z; qr[4*i+3] = tq.w;
        }
    }

    float lsum[16], acc[16];
    #pragma unroll
    for (int i = 0; i < 16; ++i) { lsum[i] = 0.f; acc[i] = 0.f; }

    const float* wsb = ws + 2048;

    const int jbeg = t ? 5 : 0;
    const int jend = t ? 9 : 5;
    for (int j = jbeg; j < jend; ++j) {   // 5 iters, last one half-masked
        const size_t base = rowbase + (size_t)j * 64;
        const float4* k4 = (const float4*)(k  + base);
        const float4* p4 = (const float4*)(pe + base);
        const float4* v4 = (const float4*)(v  + base);

        float x[16], vp[16];
        #pragma unroll
        for (int i = 0; i < 4; ++i) {
            float4 kk = k4[i], pp = p4[i], vv = v4[i];
            x [4*i+0] = qr[4*i+0] - kk.x + pp.x;
            x [4*i+1] = qr[4*i+1] - kk.y + pp.y;
            x [4*i+2] = qr[4*i+2] - kk.z + pp.z;
            x [4*i+3] = qr[4*i+3] - kk.w + pp.w;
            vp[4*i+0] = vv.x + pp.x;
            vp[4*i+1] = vv.y + pp.y;
            vp[4*i+2] = vv.z + pp.z;
            vp[4*i+3] = vv.w + pp.w;
        }

        float s[16];
        #pragma unroll
        for (int c = 0; c < 16; ++c) s[c] = 0.f;

        // MLP 16 -> 64(relu) -> 16; weights via uniform scalar loads (addresses
        // independent of j/t, so scalarization survives the divergent j-loop)
        #pragma unroll 2
        for (int o = 0; o < 64; ++o) {
            const float4* w4 = (const float4*)(ws + o * 32);
            float4 a0 = w4[0], a1 = w4[1], a2 = w4[2], a3 = w4[3];  // W1t row o
            float4 c0 = w4[4], c1 = w4[5], c2 = w4[6], c3 = w4[7];  // W2  row o
            float hv = wsb[o];
            hv = fmaf(x[0],  a0.x, hv); hv = fmaf(x[1],  a0.y, hv);
            hv = fmaf(x[2],  a0.z, hv); hv = fmaf(x[3],  a0.w, hv);
            hv = fmaf(x[4],  a1.x, hv); hv = fmaf(x[5],  a1.y, hv);
            hv = fmaf(x[6],  a1.z, hv); hv = fmaf(x[7],  a1.w, hv);
            hv = fmaf(x[8],  a2.x, hv); hv = fmaf(x[9],  a2.y, hv);
            hv = fmaf(x[10], a2.z, hv); hv = fmaf(x[11], a2.w, hv);
            hv = fmaf(x[12], a3.x, hv); hv = fmaf(x[13], a3.y, hv);
            hv = fmaf(x[14], a3.z, hv); hv = fmaf(x[15], a3.w, hv);
            hv = fmaxf(hv, 0.f);
            s[0]  = fmaf(hv, c0.x, s[0]);  s[1]  = fmaf(hv, c0.y, s[1]);
            s[2]  = fmaf(hv, c0.z, s[2]);  s[3]  = fmaf(hv, c0.w, s[3]);
            s[4]  = fmaf(hv, c1.x, s[4]);  s[5]  = fmaf(hv, c1.y, s[5]);
            s[6]  = fmaf(hv, c1.z, s[6]);  s[7]  = fmaf(hv, c1.w, s[7]);
            s[8]  = fmaf(hv, c2.x, s[8]);  s[9]  = fmaf(hv, c2.y, s[9]);
            s[10] = fmaf(hv, c2.z, s[10]); s[11] = fmaf(hv, c2.w, s[11]);
            s[12] = fmaf(hv, c3.x, s[12]); s[13] = fmaf(hv, c3.y, s[13]);
            s[14] = fmaf(hv, c3.z, s[14]); s[15] = fmaf(hv, c3.w, s[15]);
        }
        // b2 omitted: softmax over neighbors is shift-invariant in b2.

        // online softmax accumulate (|s| small: no max-subtract needed in fp32)
        #pragma unroll
        for (int c = 0; c < 16; ++c) {
            float e = __expf(s[c]);
            lsum[c] += e;
            acc[c]  = fmaf(e, vp[c], acc[c]);
        }
    }

    // pair-combine partial sums (lanes 2m <-> 2m+1): same wave, no LDS/barrier
    #pragma unroll
    for (int c = 0; c < 16; ++c) {
        lsum[c] += __shfl_xor(lsum[c], 1);
        acc[c]  += __shfl_xor(acc[c],  1);
    }

    // each lane stores its 8-channel half with STATIC indices (rule #20);
    // lane pair covers 16 contiguous channels -> coalesced 32B/lane stores
    float4* o4 = (float4*)(out + qbase + (size_t)t * 8);
    if (t == 0) {
        float4 t0, t1;
        t0.x = __fdividef(acc[0], lsum[0]); t0.y = __fdividef(acc[1], lsum[1]);
        t0.z = __fdividef(acc[2], lsum[2]); t0.w = __fdividef(acc[3], lsum[3]);
        t1.x = __fdividef(acc[4], lsum[4]); t1.y = __fdividef(acc[5], lsum[5]);
        t1.z = __fdividef(acc[6], lsum[6]); t1.w = __fdividef(acc[7], lsum[7]);
        o4[0] = t0; o4[1] = t1;
    } else {
        float4 t0, t1;
        t0.x = __fdividef(acc[8],  lsum[8]);  t0.y = __fdividef(acc[9],  lsum[9]);
        t0.z = __fdividef(acc[10], lsum[10]); t0.w = __fdividef(acc[11], lsum[11]);
        t1.x = __fdividef(acc[12], lsum[12]); t1.y = __fdividef(acc[13], lsum[13]);
        t1.z = __fdividef(acc[14], lsum[14]); t1.w = __fdividef(acc[15], lsum[15]);
        o4[0] = t0; o4[1] = t1;
    }
}

extern "C" void kernel_launch(void* const* d_in, const int* in_sizes, int n_in,
                              void* d_out, int out_size, void* d_ws, size_t ws_size,
                              hipStream_t stream) {
    const float* q  = (const float*)d_in[0];
    const float* k  = (const float*)d_in[1];
    const float* v  = (const float*)d_in[2];
    const float* pe = (const float*)d_in[3];
    const float* W1 = (const float*)d_in[4];
    const float* b1 = (const float*)d_in[5];
    const float* W2 = (const float*)d_in[6];
    // d_in[7] = b2: cancels in softmax over neighbors.
    float* out = (float*)d_out;
    float* ws  = (float*)d_ws;   // needs (2048+64)*4 = 8448 B

    pack_weights<<<1, 256, 0, stream>>>(W1, b1, W2, ws);

    const int nrows   = in_sizes[0] / 16;   // (bs*num_p)*4 heads = 262144
    const int threads = nrows * 2;          // 2 threads per row
    const int grid    = threads / 256;      // 2048 blocks, divides exactly
    subattn_kernel<<<grid, 256, 0, stream>>>(q, k, v, pe, ws, out);
}

// Round 5
// 102.443 us; speedup vs baseline: 1.5073x; 1.5073x over previous
//
#include <hip/hip_runtime.h>

typedef unsigned int uint;
typedef unsigned short ushort;
typedef __attribute__((ext_vector_type(2))) uint  u32x2;
typedef __attribute__((ext_vector_type(4))) short s16x4;
typedef __attribute__((ext_vector_type(4))) float f32x4;

#if __has_builtin(__builtin_amdgcn_mfma_f32_16x16x16bf16_1k)
#define MFMA(a,b,c) __builtin_amdgcn_mfma_f32_16x16x16bf16_1k((a),(b),(c),0,0,0)
#else
__device__ __forceinline__ f32x4 mfma_fb(s16x4 a, s16x4 b, f32x4 c){
    asm volatile("v_mfma_f32_16x16x16_bf16 %0, %1, %2, %0\n\ts_nop 7\n\ts_nop 7"
                 : "+v"(c) : "v"(a), "v"(b));
    return c;
}
#define MFMA(a,b,c) mfma_fb((a),(b),(c))
#endif

__device__ __forceinline__ uint  fbits(float f){ return __builtin_bit_cast(uint, f); }
__device__ __forceinline__ float ibits(uint u){ return __builtin_bit_cast(float, u); }

// truncation split: x ~= hi + lo, both bf16 (error ~2^-17 rel; lo*lo dropped)
__device__ __forceinline__ void split4(f32x4 x, s16x4& hi, s16x4& lo){
    uint b0=fbits(x.x), b1=fbits(x.y), b2=fbits(x.z), b3=fbits(x.w);
    u32x2 h; h.x = (b0>>16) | (b1 & 0xFFFF0000u); h.y = (b2>>16) | (b3 & 0xFFFF0000u);
    float l0 = x.x - ibits(b0 & 0xFFFF0000u);
    float l1 = x.y - ibits(b1 & 0xFFFF0000u);
    float l2 = x.z - ibits(b2 & 0xFFFF0000u);
    float l3 = x.w - ibits(b3 & 0xFFFF0000u);
    u32x2 l; l.x = (fbits(l0)>>16) | (fbits(l1) & 0xFFFF0000u);
    l.y = (fbits(l2)>>16) | (fbits(l3) & 0xFFFF0000u);
    hi = __builtin_bit_cast(s16x4, h);
    lo = __builtin_bit_cast(s16x4, l);
}

// ---------------- weight packing into per-lane MFMA fragments ----------------
// uint2 units: [0..255] W1hi  [256..511] W1lo  [512..767] W2hi  [768..1023] W2lo
//   (index = t*64 + lane). Then floats at 2048+: b1 fragments, f32x4 per (t,lane).
// W1 frag (A of H^T = W1^T X^T, tile t): lane holds A[m=lane&15][k=4g+j]
//   = W1^T[16t+m][4g+j] = W1[(4g+j)*64 + 16t+m].
// W2 frag (A of S^T = W2^T H^T, K-step t): lane holds W2^T[m][16t+4g+j]
//   = W2[(16t+4g+j)*16 + m].
__global__ void pack_weights(const float* __restrict__ W1, const float* __restrict__ b1,
                             const float* __restrict__ W2, float* __restrict__ ws)
{
    const int e = threadIdx.x;          // 256 = 4 tiles * 64 lanes
    const int t = e >> 6, l = e & 63;
    const int g = l >> 4, m = l & 15;

    float w1v[4], w2v[4];
    #pragma unroll
    for (int j = 0; j < 4; ++j) {
        w1v[j] = W1[(4*g + j)*64 + 16*t + m];
        w2v[j] = W2[(16*t + 4*g + j)*16 + m];
    }
    ushort h1[4], o1[4], h2[4], o2[4];
    #pragma unroll
    for (int j = 0; j < 4; ++j) {
        uint u1 = fbits(w1v[j]);
        ushort a = (ushort)((u1 + 0x7FFFu + ((u1>>16)&1u)) >> 16);      // RNE hi
        float  r = w1v[j] - ibits(((uint)a) << 16);
        uint ur = fbits(r);
        ushort b = (ushort)((ur + 0x7FFFu + ((ur>>16)&1u)) >> 16);      // RNE lo
        h1[j] = a; o1[j] = b;
        uint u2 = fbits(w2v[j]);
        a = (ushort)((u2 + 0x7FFFu + ((u2>>16)&1u)) >> 16);
        r = w2v[j] - ibits(((uint)a) << 16);
        ur = fbits(r);
        b = (ushort)((ur + 0x7FFFu + ((ur>>16)&1u)) >> 16);
        h2[j] = a; o2[j] = b;
    }
    u32x2* wp = (u32x2*)ws;
    u32x2 x;
    x.x = (uint)h1[0] | ((uint)h1[1] << 16); x.y = (uint)h1[2] | ((uint)h1[3] << 16);
    wp[e] = x;
    x.x = (uint)o1[0] | ((uint)o1[1] << 16); x.y = (uint)o1[2] | ((uint)o1[3] << 16);
    wp[256 + e] = x;
    x.x = (uint)h2[0] | ((uint)h2[1] << 16); x.y = (uint)h2[2] | ((uint)h2[3] << 16);
    wp[512 + e] = x;
    x.x = (uint)o2[0] | ((uint)o2[1] << 16); x.y = (uint)o2[2] | ((uint)o2[3] << 16);
    wp[768 + e] = x;

    f32x4 bb;
    bb.x = b1[16*t + 4*g + 0]; bb.y = b1[16*t + 4*g + 1];
    bb.z = b1[16*t + 4*g + 2]; bb.w = b1[16*t + 4*g + 3];
    ((f32x4*)(ws + 2048))[e] = bb;
}

// ---------------- main kernel ----------------
// One wave = 16 rows (r = bp*4+h). Lane (g = l>>4, n = l&15) owns row n of the
// group and channel chunk 4g..4g+3 for loads/stores. Swapped-operand GEMMs:
//   C1'[t] = W1t_frag x X_frag  ->  lane holds H[row n][hid 16t+4g+r]
// which is EXACTLY the B-fragment of K-step t of
//   C2'   += W2t_frag x H_frag  ->  lane holds S[row n][chan 4g+r]
// so zero cross-lane data movement between layers. hi/lo bf16 split on both
// operands (3 MFMAs/tile) keeps fp32-level accuracy. b2 cancels in softmax.
__global__ __launch_bounds__(256) __attribute__((amdgpu_waves_per_eu(4, 4)))
void subattn_mfma(const float* __restrict__ q, const float* __restrict__ k,
                  const float* __restrict__ v, const float* __restrict__ pe,
                  const float* __restrict__ ws, float* __restrict__ out)
{
    const int tid = threadIdx.x;
    const int wv  = tid >> 6;
    const int l   = tid & 63;
    const int n   = l & 15, g = l >> 4;
    const int grp = blockIdx.x * 4 + wv;
    const int rg  = grp * 16 + n;            // global row = bp*4 + h
    const int bp  = rg >> 2, h = rg & 3;

    // weight fragments (per-lane, static for the whole kernel)
    const u32x2* wp = (const u32x2*)ws;
    const f32x4* bptr = (const f32x4*)(ws + 2048);
    s16x4 w1h[4], w1l[4], w2h[4], w2l[4];
    f32x4 b1f[4];
    #pragma unroll
    for (int t = 0; t < 4; ++t) {
        w1h[t] = __builtin_bit_cast(s16x4, wp[      t*64 + l]);
        w1l[t] = __builtin_bit_cast(s16x4, wp[256 + t*64 + l]);
        w2h[t] = __builtin_bit_cast(s16x4, wp[512 + t*64 + l]);
        w2l[t] = __builtin_bit_cast(s16x4, wp[768 + t*64 + l]);
        b1f[t] = bptr[t*64 + l];
    }

    const size_t qoff  = (size_t)rg * 16 + g * 4;
    const f32x4  qf    = *(const f32x4*)(q + qoff);
    const size_t kbase = (size_t)bp * 576 + h * 16 + g * 4;   // 9*64 per bp

    f32x4 lsum = {0.f, 0.f, 0.f, 0.f};
    f32x4 acc  = {0.f, 0.f, 0.f, 0.f};

    #pragma unroll 3
    for (int j = 0; j < 9; ++j) {
        const size_t off = kbase + (size_t)j * 64;
        f32x4 kf = *(const f32x4*)(k  + off);
        f32x4 pf = *(const f32x4*)(pe + off);
        f32x4 vf = *(const f32x4*)(v  + off);

        f32x4 x = qf - kf + pf;
        s16x4 xh, xl; split4(x, xh, xl);

        f32x4 c2 = {0.f, 0.f, 0.f, 0.f};
        #pragma unroll
        for (int t = 0; t < 4; ++t) {
            f32x4 c1 = b1f[t];
            c1 = MFMA(w1l[t], xh, c1);
            c1 = MFMA(w1h[t], xl, c1);
            c1 = MFMA(w1h[t], xh, c1);
            f32x4 hr;
            hr.x = fmaxf(c1.x, 0.f); hr.y = fmaxf(c1.y, 0.f);
            hr.z = fmaxf(c1.z, 0.f); hr.w = fmaxf(c1.w, 0.f);
            s16x4 hh, hl; split4(hr, hh, hl);
            c2 = MFMA(w2l[t], hh, c2);
            c2 = MFMA(w2h[t], hl, c2);
            c2 = MFMA(w2h[t], hh, c2);
        }

        f32x4 vp = vf + pf;
        float e0 = __expf(c2.x), e1 = __expf(c2.y);
        float e2 = __expf(c2.z), e3 = __expf(c2.w);
        lsum.x += e0; lsum.y += e1; lsum.z += e2; lsum.w += e3;
        acc.x = fmaf(e0, vp.x, acc.x); acc.y = fmaf(e1, vp.y, acc.y);
        acc.z = fmaf(e2, vp.z, acc.z); acc.w = fmaf(e3, vp.w, acc.w);
    }

    f32x4 o;
    o.x = __fdividef(acc.x, lsum.x); o.y = __fdividef(acc.y, lsum.y);
    o.z = __fdividef(acc.z, lsum.z); o.w = __fdividef(acc.w, lsum.w);
    *(f32x4*)(out + qoff) = o;
}

extern "C" void kernel_launch(void* const* d_in, const int* in_sizes, int n_in,
                              void* d_out, int out_size, void* d_ws, size_t ws_size,
                              hipStream_t stream) {
    const float* q  = (const float*)d_in[0];
    const float* k  = (const float*)d_in[1];
    const float* v  = (const float*)d_in[2];
    const float* pe = (const float*)d_in[3];
    const float* W1 = (const float*)d_in[4];
    const float* b1 = (const float*)d_in[5];
    const float* W2 = (const float*)d_in[6];
    // d_in[7] = b2: cancels in softmax over neighbors.
    float* out = (float*)d_out;
    float* ws  = (float*)d_ws;   // uses 12 KB: 8 KB bf16 frags + 4 KB b1 frags

    pack_weights<<<1, 256, 0, stream>>>(W1, b1, W2, ws);

    const int nrows  = in_sizes[0] / 16;   // (bs*num_p)*4 heads = 262144
    const int groups = nrows / 16;         // 16384 wave-groups
    const int grid   = groups / 4;         // 4 waves per 256-thread block
    subattn_mfma<<<grid, 256, 0, stream>>>(q, k, v, pe, ws, out);
}